// Round 4
// baseline (2143.694 us; speedup 1.0000x reference)
//
#include <hip/hip_runtime.h>
#include <hip/hip_bf16.h>
#include <math.h>

#define B_ 2
#define T_ 512
#define C_ 512
#define L_ 3
#define NH_ 8
#define SD_ 65
#define AD_ 17
#define H4_ 2048
#define S_ 1536
#define D_ 64

typedef __hip_bfloat16 bf16;
typedef __bf16 bf16x8 __attribute__((ext_vector_type(8)));
typedef float f32x4 __attribute__((ext_vector_type(4)));

// ---- output element offsets (f32 elements) ----
#define OFF_STATE  0
#define OFF_ACTION 66560          // B*T*SD
#define OFF_RTG    83968          // + B*T*AD
#define OFF_W      84992          // + B*T
#define OFF_M      113331200ULL   // + L*B*NH*S*S
#define OUT_TOTAL  132205568ULL

// ---- workspace byte offsets (total 15,728,640 B — keep small: ws_size may be tight) ----
#define WS_HF     0ULL            // B*S*C f32 = 6,291,456
#define WS_Q      6291456ULL      // B*S*C bf16 = 3,145,728 (att reuses after scores)
#define WS_K      9437184ULL
#define WS_VT     12582912ULL     // [B,NH,D,S] bf16

// ---- convert 8 contiguous elements (bf16 or f32 source) to MFMA bf16x8 frag ----
__device__ __forceinline__ bf16x8 load8(const char* p, int is_f32) {
    if (!is_f32) return *(const bf16x8*)p;
    const float* f = (const float*)p;
    bf16x8 r;
#pragma unroll
    for (int j = 0; j < 8; j++) {
        union { __hip_bfloat16 h; __bf16 b; } u;
        u.h = __float2bfloat16(f[j]);
        r[j] = u.b;
    }
    return r;
}

__device__ __forceinline__ void block_reduce2(float& s1, float& s2, float* lds) {
    for (int off = 32; off >= 1; off >>= 1) {
        s1 += __shfl_xor(s1, off, 64);
        s2 += __shfl_xor(s2, off, 64);
    }
    int wave = threadIdx.x >> 6;
    if ((threadIdx.x & 63) == 0) { lds[wave] = s1; lds[wave + 4] = s2; }
    __syncthreads();
    s1 = lds[0] + lds[1] + lds[2] + lds[3];
    s2 = lds[4] + lds[5] + lds[6] + lds[7];
}

// ---------------- embedding + LN (all params f32, straight from d_in) ----------------
__global__ __launch_bounds__(256) void embed_kernel(
    const int* __restrict__ timesteps, const int* __restrict__ states,
    const int* __restrict__ actions, const float* __restrict__ rtg,
    const float* __restrict__ Wt, const float* __restrict__ Ws, const float* __restrict__ Wa,
    const float* __restrict__ Wr_w, const float* __restrict__ Wr_b,
    const float* __restrict__ g, const float* __restrict__ bta,
    float* __restrict__ h)
{
    int bid = blockIdx.x;           // b*S + s
    int b = bid / S_, s = bid % S_;
    int t = s / 3, kind = s % 3;
    int tid = threadIdx.x;
    int bt = b * T_ + t;
    float vals[2];
    float s1 = 0.f, s2 = 0.f;
    int ts = timesteps[bt];
    for (int i = 0; i < 2; i++) {
        int c = tid + i * 256;
        float te = Wt[(size_t)ts * C_ + c];
        float v;
        if (kind == 0)
            v = rtg[bt] * Wr_w[c] + Wr_b[c] + te;
        else if (kind == 1)
            v = Ws[(size_t)states[bt] * C_ + c] + te;
        else
            v = Wa[(size_t)actions[bt] * C_ + c] + te;
        vals[i] = v; s1 += v; s2 += v * v;
    }
    __shared__ float lds[8];
    block_reduce2(s1, s2, lds);
    float mean = s1 / C_;
    float rstd = rsqrtf(s2 / C_ - mean * mean + 1e-5f);
    size_t rowoff = (size_t)bid * C_;
    for (int i = 0; i < 2; i++) {
        int c = tid + i * 256;
        h[rowoff + c] = (vals[i] - mean) * rstd * g[c] + bta[c];
    }
}

// ---------------- in-place LayerNorm on h (f32) ----------------
__global__ __launch_bounds__(256) void ln_kernel(
    float* __restrict__ h, const float* __restrict__ g, const float* __restrict__ bta)
{
    int bid = blockIdx.x;
    int tid = threadIdx.x;
    size_t rowoff = (size_t)bid * C_;
    float vals[2]; float s1 = 0.f, s2 = 0.f;
    for (int i = 0; i < 2; i++) {
        float v = h[rowoff + tid + i * 256];
        vals[i] = v; s1 += v; s2 += v * v;
    }
    __shared__ float lds[8];
    block_reduce2(s1, s2, lds);
    float mean = s1 / C_;
    float rstd = rsqrtf(s2 / C_ - mean * mean + 1e-5f);
    for (int i = 0; i < 2; i++) {
        int c = tid + i * 256;
        h[rowoff + c] = (vals[i] - mean) * rstd * g[c] + bta[c];
    }
}

// ---------------- generic GEMM: out = A[M,K] @ W[N,K]^T (+bias) ----------------
// A and W may each be bf16 or f32 (flags). bias is f32 (or null).
// epi 0: bf16 row-major out      epi 1: transposed bf16 write to vT[b,h,d,s]
// epi 2: f32 in-place resid add: out_f32[idx] = acc + bias + out_f32[idx]
// epi 3: gelu -> f32 out
__global__ __launch_bounds__(256) void gemm_bt_kernel(
    const char* __restrict__ A, int a_f32, const char* __restrict__ W, int w_f32,
    const float* __restrict__ bias, int M, int N, int K, int epi,
    bf16* __restrict__ out_bf, float* __restrict__ out_f32)
{
    int tid = threadIdx.x;
    int wave = tid >> 6, lane = tid & 63;
    int quad = lane >> 4, l16 = lane & 15;
    int m0 = blockIdx.y * 64 + (wave >> 1) * 32;
    int n0 = blockIdx.x * 64 + (wave & 1) * 32;
    f32x4 acc[2][2] = {};
    size_t ea = a_f32 ? 4 : 2, ew = w_f32 ? 4 : 2;
    const char* Arow0 = A + ((size_t)(m0 + l16) * K + quad * 8) * ea;
    const char* Arow1 = Arow0 + (size_t)16 * K * ea;
    const char* Wrow0 = W + ((size_t)(n0 + l16) * K + quad * 8) * ew;
    const char* Wrow1 = Wrow0 + (size_t)16 * K * ew;
    for (int k0 = 0; k0 < K; k0 += 32) {
        bf16x8 a0 = load8(Arow0 + (size_t)k0 * ea, a_f32);
        bf16x8 a1 = load8(Arow1 + (size_t)k0 * ea, a_f32);
        bf16x8 b0 = load8(Wrow0 + (size_t)k0 * ew, w_f32);
        bf16x8 b1 = load8(Wrow1 + (size_t)k0 * ew, w_f32);
        acc[0][0] = __builtin_amdgcn_mfma_f32_16x16x32_bf16(a0, b0, acc[0][0], 0, 0, 0);
        acc[0][1] = __builtin_amdgcn_mfma_f32_16x16x32_bf16(a0, b1, acc[0][1], 0, 0, 0);
        acc[1][0] = __builtin_amdgcn_mfma_f32_16x16x32_bf16(a1, b0, acc[1][0], 0, 0, 0);
        acc[1][1] = __builtin_amdgcn_mfma_f32_16x16x32_bf16(a1, b1, acc[1][1], 0, 0, 0);
    }
    for (int mt = 0; mt < 2; mt++)
    for (int nt = 0; nt < 2; nt++) {
        int col = n0 + nt * 16 + l16;
        float bia = bias ? bias[col] : 0.f;
        for (int r = 0; r < 4; r++) {
            int row = m0 + mt * 16 + quad * 4 + r;
            float v = acc[mt][nt][r] + bia;
            size_t idx = (size_t)row * N + col;
            if (epi == 0) {
                out_bf[idx] = __float2bfloat16(v);
            } else if (epi == 1) {
                int bb = row / S_, ss = row % S_;
                int hh = col / D_, dd = col % D_;
                out_bf[(((size_t)bb * NH_ + hh) * D_ + dd) * S_ + ss] = __float2bfloat16(v);
            } else if (epi == 2) {
                out_f32[idx] = v + out_f32[idx];
            } else {
                out_f32[idx] = 0.5f * v * (1.f + erff(v * 0.70710678f));
            }
        }
    }
}

// ---------------- attention scores + softmax -> w (f32, into d_out) ----------------
__global__ __launch_bounds__(256) void attn_scores_kernel(
    const bf16* __restrict__ q, const bf16* __restrict__ k, float* __restrict__ w_out)
{
    int strip = blockIdx.x;          // 16-row strip
    int bh = blockIdx.y;             // b*NH + h
    int b = bh / NH_, h = bh % NH_;
    int s0 = strip * 16;
    int tid = threadIdx.x;
    int wave = tid >> 6, lane = tid & 63, quad = lane >> 4, l16 = lane & 15;
    int ja = 3 * ((s0 + 15) / 3) + 2;                // max allowed j in strip
    int jtiles = ja / 16 + 1;
    int jlen = jtiles * 16;
    __shared__ bf16 sc[16][1552];

    const bf16* qrow = q + ((size_t)(b * S_ + s0 + l16)) * C_ + h * D_ + quad * 8;
    bf16x8 a0 = *(const bf16x8*)(qrow);
    bf16x8 a1 = *(const bf16x8*)(qrow + 32);
    for (int jt = wave; jt < jtiles; jt += 4) {
        const bf16* krow = k + ((size_t)(b * S_ + jt * 16 + l16)) * C_ + h * D_ + quad * 8;
        bf16x8 b0 = *(const bf16x8*)(krow);
        bf16x8 b1 = *(const bf16x8*)(krow + 32);
        f32x4 acc = {0.f, 0.f, 0.f, 0.f};
        acc = __builtin_amdgcn_mfma_f32_16x16x32_bf16(a0, b0, acc, 0, 0, 0);
        acc = __builtin_amdgcn_mfma_f32_16x16x32_bf16(a1, b1, acc, 0, 0, 0);
        for (int r = 0; r < 4; r++)
            sc[quad * 4 + r][jt * 16 + l16] = __float2bfloat16(acc[r] * 0.125f);
    }
    __syncthreads();

    int r = tid >> 4, c0 = tid & 15;
    int i = s0 + r;
    int lim = 3 * (i / 3) + 2;       // max allowed column for this row
    float m = -3.0e38f;
    for (int c = c0; c <= lim; c += 16) m = fmaxf(m, __bfloat162float(sc[r][c]));
    for (int off = 8; off >= 1; off >>= 1) m = fmaxf(m, __shfl_xor(m, off, 16));
    float sum = 0.f;
    float ev[96];
    int nc = 0;
    for (int c = c0; c < jlen; c += 16) {
        float e = (c <= lim) ? __expf(__bfloat162float(sc[r][c]) - m) : 0.f;
        sum += e;
        ev[nc++] = e;
    }
    for (int off = 8; off >= 1; off >>= 1) sum += __shfl_xor(sum, off, 16);
    float inv = 1.f / sum;
    float* wrow = w_out + ((size_t)bh * S_ + i) * S_;
    nc = 0;
    for (int c = c0; c < jlen; c += 16)
        wrow[c] = ev[nc++] * inv;
    // region beyond jlen stays exact zero via the d_out memset
}

// ---------------- att = w @ v  (w f32 in d_out; vT layout [B,NH,D,S]) ----------------
__global__ __launch_bounds__(256) void attn_pv_kernel(
    const float* __restrict__ w, const bf16* __restrict__ vT, bf16* __restrict__ att)
{
    int strip = blockIdx.x;          // 64-row strip
    int bh = blockIdx.y;
    int b = bh / NH_, h = bh % NH_;
    int tid = threadIdx.x;
    int wave = tid >> 6, lane = tid & 63, quad = lane >> 4, l16 = lane & 15;
    int s0 = strip * 64 + wave * 16;
    int ja = 3 * ((s0 + 15) / 3) + 2;
    int kend = ((ja + 1 + 31) / 32) * 32;
    if (kend > S_) kend = S_;
    const float* wrow = w + ((size_t)bh * S_ + s0 + l16) * S_ + quad * 8;
    const bf16* vbase = vT + ((size_t)bh * D_ + l16) * S_ + quad * 8;
    f32x4 acc[4] = {};
    for (int k0 = 0; k0 < kend; k0 += 32) {
        bf16x8 a = load8((const char*)(wrow + k0), 1);
        for (int nt = 0; nt < 4; nt++) {
            bf16x8 bv = *(const bf16x8*)(vbase + (size_t)nt * 16 * S_ + k0);
            acc[nt] = __builtin_amdgcn_mfma_f32_16x16x32_bf16(a, bv, acc[nt], 0, 0, 0);
        }
    }
    for (int nt = 0; nt < 4; nt++)
    for (int r = 0; r < 4; r++) {
        int s = s0 + quad * 4 + r;
        int d = nt * 16 + l16;
        att[((size_t)(b * S_ + s)) * C_ + h * D_ + d] = __float2bfloat16(acc[nt][r]);
    }
}

// ---------------- prediction heads (f32 weights) ----------------
__global__ __launch_bounds__(256) void heads_kernel(
    const float* __restrict__ h,
    const float* __restrict__ pr_w, const float* __restrict__ pr_b,
    const float* __restrict__ ps_w, const float* __restrict__ ps_b,
    const float* __restrict__ pa_w, const float* __restrict__ pa_b,
    float* __restrict__ out)
{
    int bid = blockIdx.x;
    int b = bid / T_, t = bid % T_;
    __shared__ float hs[C_], ha[C_];
    int tid = threadIdx.x;
    for (int i = tid; i < C_; i += 256) {
        hs[i] = h[((size_t)(b * S_ + 2 * T_ + t)) * C_ + i];   // chunk 2
        ha[i] = h[((size_t)(b * S_ + T_ + t)) * C_ + i];       // chunk 1
    }
    __syncthreads();
    if (tid < SD_) {
        float acc = ps_b[tid];
        for (int kk = 0; kk < C_; kk++) acc += ps_w[tid * C_ + kk] * hs[kk];
        out[OFF_STATE + ((size_t)(b * T_ + t)) * SD_ + tid] = acc;
    } else if (tid < SD_ + AD_) {
        int n = tid - SD_;
        float acc = pa_b[n];
        for (int kk = 0; kk < C_; kk++) acc += pa_w[n * C_ + kk] * ha[kk];
        out[OFF_ACTION + ((size_t)(b * T_ + t)) * AD_ + n] = acc;
    } else if (tid == SD_ + AD_) {
        float acc = pr_b[0];
        for (int kk = 0; kk < C_; kk++) acc += pr_w[kk] * hs[kk];
        out[OFF_RTG + (size_t)(b * T_ + t)] = acc;
    }
}

extern "C" void kernel_launch(void* const* d_in, const int* in_sizes, int n_in,
                              void* d_out, int out_size, void* d_ws, size_t ws_size,
                              hipStream_t stream) {
    const int* timesteps = (const int*)d_in[0];
    const int* states    = (const int*)d_in[1];
    const int* actions   = (const int*)d_in[2];
    const float* rtg    = (const float*)d_in[3];
    const float* Wt     = (const float*)d_in[4];
    const float* Ws     = (const float*)d_in[5];
    const float* Wa     = (const float*)d_in[6];
    const float* Wr_w   = (const float*)d_in[7];
    const float* Wr_b   = (const float*)d_in[8];
    const float* ln_e_g = (const float*)d_in[9];
    const float* ln_e_b = (const float*)d_in[10];
    const float* Wq     = (const float*)d_in[11];
    const float* bq     = (const float*)d_in[12];
    const float* Wk     = (const float*)d_in[13];
    const float* bk     = (const float*)d_in[14];
    const float* Wv     = (const float*)d_in[15];
    const float* bv     = (const float*)d_in[16];
    const float* Wo     = (const float*)d_in[17];
    const float* bo     = (const float*)d_in[18];
    const float* W1     = (const float*)d_in[19];
    const float* b1     = (const float*)d_in[20];
    const float* W2     = (const float*)d_in[21];
    const float* b2     = (const float*)d_in[22];
    const float* ln1_g  = (const float*)d_in[23];
    const float* ln1_b  = (const float*)d_in[24];
    const float* ln2_g  = (const float*)d_in[25];
    const float* ln2_b  = (const float*)d_in[26];
    const float* pr_w   = (const float*)d_in[27];
    const float* pr_b   = (const float*)d_in[28];
    const float* ps_w   = (const float*)d_in[29];
    const float* ps_b   = (const float*)d_in[30];
    const float* pa_w   = (const float*)d_in[31];
    const float* pa_b   = (const float*)d_in[32];

    float* out = (float*)d_out;
    char* ws = (char*)d_ws;
    float* h_f  = (float*)(ws + WS_HF);
    bf16* q_bf  = (bf16*)(ws + WS_Q);
    bf16* att_bf = q_bf;              // reuse: q dead once scores are built
    bf16* k_bf  = (bf16*)(ws + WS_K);
    bf16* vT    = (bf16*)(ws + WS_VT);

    const int M = B_ * S_;   // 3072

    // zeros for masked attention region of w (f32 out)
    hipMemsetAsync(d_out, 0, (size_t)out_size * sizeof(float), stream);

    embed_kernel<<<B_ * S_, 256, 0, stream>>>(timesteps, states, actions, rtg,
                                              Wt, Ws, Wa, Wr_w, Wr_b, ln_e_g, ln_e_b, h_f);

    for (int l = 0; l < L_; l++) {
        const float* Wq_l = Wq + (size_t)l * C_ * C_;
        const float* Wk_l = Wk + (size_t)l * C_ * C_;
        const float* Wv_l = Wv + (size_t)l * C_ * C_;
        const float* Wo_l = Wo + (size_t)l * C_ * C_;
        const float* W1_l = W1 + (size_t)l * H4_ * C_;
        const float* W2_l = W2 + (size_t)l * C_ * H4_;
        float* w_l = out + OFF_W + (size_t)l * B_ * NH_ * (size_t)S_ * S_;
        float* m_l = out + OFF_M + (size_t)l * B_ * S_ * H4_;

        gemm_bt_kernel<<<dim3(C_ / 64, M / 64), 256, 0, stream>>>(
            (const char*)h_f, 1, (const char*)Wq_l, 1, bq + l * C_, M, C_, C_, 0, q_bf, nullptr);
        gemm_bt_kernel<<<dim3(C_ / 64, M / 64), 256, 0, stream>>>(
            (const char*)h_f, 1, (const char*)Wk_l, 1, bk + l * C_, M, C_, C_, 0, k_bf, nullptr);
        gemm_bt_kernel<<<dim3(C_ / 64, M / 64), 256, 0, stream>>>(
            (const char*)h_f, 1, (const char*)Wv_l, 1, bv + l * C_, M, C_, C_, 1, vT, nullptr);

        attn_scores_kernel<<<dim3(S_ / 16, B_ * NH_), 256, 0, stream>>>(q_bf, k_bf, w_l);
        attn_pv_kernel<<<dim3(S_ / 64, B_ * NH_), 256, 0, stream>>>(w_l, vT, att_bf);

        gemm_bt_kernel<<<dim3(C_ / 64, M / 64), 256, 0, stream>>>(
            (const char*)att_bf, 0, (const char*)Wo_l, 1, bo + l * C_, M, C_, C_, 2, nullptr, h_f);
        ln_kernel<<<B_ * S_, 256, 0, stream>>>(h_f, ln1_g + l * C_, ln1_b + l * C_);

        gemm_bt_kernel<<<dim3(H4_ / 64, M / 64), 256, 0, stream>>>(
            (const char*)h_f, 1, (const char*)W1_l, 1, b1 + l * H4_, M, H4_, C_, 3, nullptr, m_l);
        gemm_bt_kernel<<<dim3(C_ / 64, M / 64), 256, 0, stream>>>(
            (const char*)m_l, 1, (const char*)W2_l, 1, b2 + l * C_, M, C_, H4_, 2, nullptr, h_f);
        ln_kernel<<<B_ * S_, 256, 0, stream>>>(h_f, ln2_g + l * C_, ln2_b + l * C_);
    }

    heads_kernel<<<B_ * T_, 256, 0, stream>>>(h_f, pr_w, pr_b, ps_w, ps_b, pa_w, pa_b, out);
}